// Round 9
// baseline (433.852 us; speedup 1.0000x reference)
//
#include <hip/hip_runtime.h>
#include <hip/hip_bf16.h>

// SegmentConv2d: fake-quant-int8 (global for x, per-128-oc-chunk for w) + 3x3 pad1 conv + bias.
// int8 path: quantize to real int8, conv with mfma_i32_16x16x64_i8 (exact int accum),
// scale+bias epilogue.
//
// Shapes: x[8][256][128][128] f32, w[512][256][3][3] f32, bias[512], out[8][512][128][128] f32.
//
// ws layout:
//   [0..63]           : amax[5] (uint bits, written by k_amax2 - no atomics)
//   [64..79]          : 16B zeros (OOB redirect for global_load_lds)
//   [256..13567]      : per-block amax partials float[3328] (x: 0..2047, w: 2048..3199)
//   [16384..)         : qx int8 NHWC  [n][h][w][c]  = 33,554,432 B
//   [16384+32M..)     : qw int8       [r*3+s][oc][c] = 1,179,648 B

typedef int i32x4 __attribute__((ext_vector_type(4)));

__device__ __forceinline__ void llds16(const void* g, void* l) {
    __builtin_amdgcn_global_load_lds(
        (const __attribute__((address_space(1))) void*)g,
        (__attribute__((address_space(3))) void*)l,
        16, 0, 0);
}

__device__ __forceinline__ float f4max(float4 v) {
    return fmaxf(fmaxf(fabsf(v.x), fabsf(v.y)), fmaxf(fabsf(v.z), fabsf(v.w)));
}

// ---------------- amax stage 1: per-block partial maxima (NO atomics) ----------------
__global__ __launch_bounds__(256) void k_amax(const float4* __restrict__ x,
                                              const float4* __restrict__ w4,
                                              float* __restrict__ part) {
    __shared__ float red[4];
    int t = threadIdx.x;
    float m = 0.f;
    if (blockIdx.x < 2048) {
        int tid = blockIdx.x * 256 + t;
        float4 v[16];
#pragma unroll
        for (int k = 0; k < 16; ++k)
            v[k] = x[(size_t)tid + (size_t)k * 524288];
#pragma unroll
        for (int k = 0; k < 16; ++k) m = fmaxf(m, f4max(v[k]));
    } else {
        int b = blockIdx.x - 2048;          // 0..1151
        int chunk = b / 288;
        int tid = (b - chunk * 288) * 256 + t;
        m = f4max(w4[(size_t)chunk * 73728 + tid]);
    }
    for (int off = 32; off > 0; off >>= 1) m = fmaxf(m, __shfl_xor(m, off, 64));
    if ((t & 63) == 0) red[t >> 6] = m;
    __syncthreads();
    if (t == 0)
        part[blockIdx.x] = fmaxf(fmaxf(red[0], red[1]), fmaxf(red[2], red[3]));
}

// ---------------- amax stage 2: reduce partials -> amaxb[0..4] ----------------
__global__ __launch_bounds__(256) void k_amax2(const float* __restrict__ part,
                                               unsigned* __restrict__ amaxb) {
    __shared__ float red[4];
    int t = threadIdx.x;
    float m = 0.f;
#pragma unroll
    for (int k = 0; k < 8; ++k) m = fmaxf(m, part[t + k * 256]);
    for (int off = 32; off > 0; off >>= 1) m = fmaxf(m, __shfl_xor(m, off, 64));
    if ((t & 63) == 0) red[t >> 6] = m;
    __syncthreads();
    if (t == 0)
        amaxb[0] = __float_as_uint(fmaxf(fmaxf(red[0], red[1]), fmaxf(red[2], red[3])));
    // w: one wave per chunk, 288 partials each
    int c = t >> 6, l = t & 63;
    float wm = 0.f;
#pragma unroll
    for (int k = 0; k < 5; ++k) {
        int i = l + k * 64;
        if (i < 288) wm = fmaxf(wm, part[2048 + c * 288 + i]);
    }
    for (int off = 32; off > 0; off >>= 1) wm = fmaxf(wm, __shfl_xor(wm, off, 64));
    if (l == 0) amaxb[1 + c] = __float_as_uint(wm);
}

// ---------------- quantize x : NCHW f32 -> NHWC int8 ----------------
__global__ __launch_bounds__(256) void k_quant_x(const float* __restrict__ x,
                                                 signed char* __restrict__ qx,
                                                 const unsigned* __restrict__ amaxb) {
    float inv = 127.0f / fmaxf(__uint_as_float(amaxb[0]), 1e-12f);
    int row = blockIdx.x;                 // n*128 + h
    int n = row >> 7, h = row & 127;
    int t = threadIdx.x;
    int w4 = t & 31, cg = t >> 5;         // w4: float4 slot along w; cg in [0,8)
    const float* base = x + (size_t)n * 256 * 16384 + (size_t)h * 128 + w4 * 4;
#pragma unroll
    for (int pp = 0; pp < 2; ++pp) {
        int c0 = pp * 128 + cg * 16;
        float4 v[16];
#pragma unroll
        for (int j = 0; j < 16; ++j)
            v[j] = *(const float4*)(base + (size_t)(c0 + j) * 16384);
#pragma unroll
        for (int i = 0; i < 4; ++i) {
            unsigned wds[4];
#pragma unroll
            for (int jg = 0; jg < 4; ++jg) {
                unsigned u = 0;
#pragma unroll
                for (int jj = 0; jj < 4; ++jj) {
                    float f = (&v[jg * 4 + jj].x)[i];
                    int q = (int)fminf(fmaxf(rintf(f * inv), -128.f), 127.f);
                    u |= ((unsigned)(q & 255)) << (8 * jj);
                }
                wds[jg] = u;
            }
            *(uint4*)&qx[(size_t)row * 32768 + (size_t)(w4 * 4 + i) * 256 + c0] =
                make_uint4(wds[0], wds[1], wds[2], wds[3]);
        }
    }
}

// ---------------- quantize w : OIHW f32 -> [rs][oc][c] int8 ----------------
__global__ void k_quant_w(const float* __restrict__ wsrc, signed char* __restrict__ qw,
                          const unsigned* __restrict__ amaxb) {
    int idx = blockIdx.x * 256 + threadIdx.x;   // 131072 = 512 blocks
    int oc = idx >> 8, c = idx & 255;
    float inv = 127.0f / fmaxf(__uint_as_float(amaxb[1 + (oc >> 7)]), 1e-12f);
    const float* src = wsrc + (size_t)idx * 9;
    float v[9];
#pragma unroll
    for (int rs = 0; rs < 9; ++rs) v[rs] = src[rs];
#pragma unroll
    for (int rs = 0; rs < 9; ++rs) {
        float qf = fminf(fmaxf(rintf(v[rs] * inv), -128.f), 127.f);
        qw[((size_t)(rs * 512 + oc)) * 256 + c] = (signed char)(int)qf;
    }
}

// ---------------- conv : implicit GEMM with mfma_i32_16x16x64_i8 ----------------
// Round-9: round-6 tile/structure (best so far: grid 2048, block 256 = 4 waves,
// 128oc x 256px tile, wave = 128oc x 64px), with LDS shrunk 58 -> 48.5 KB for
// THREE blocks/CU (12 waves): rounds 7/8 proved 1-block lockstep pipelines serialize
// (172/185us); round 6's 2-block overlap gave 155. More independent blocks = more
// pipe overlap (MFMA 78us floor, LDS-read 69us, HBM 50us -- none saturated at 44%).
// wt is staged per SINGLE (r,s) plane (8 KB) into a ping-pong pair, issued at the
// top of each phase so its latency hides under that phase's 32 MFMAs; ONE barrier
// per phase (its vmcnt(0) drain doubles as stage-arrival). xs stays single-buffered
// per cb (extra barrier pair at the 4 cb boundaries only). 36 phases, ~40 barriers.
// Fragment LDS reads XOR-swizzled (8-way -> 2-way) via permuted GLOBAL source q4.
__global__ __launch_bounds__(256, 3) void k_conv(
    const signed char* __restrict__ qx, const signed char* __restrict__ qw,
    const signed char* __restrict__ zb, const unsigned* __restrict__ amaxb,
    const float* __restrict__ bias, float* __restrict__ out) {
    __shared__ __align__(16) signed char xs[4 * 8320];     // 33280 B
    __shared__ __align__(16) signed char wt[2][128 * 64];  // 2 x 8192 B
    int orig = blockIdx.x;                      // 0..2047, nwg % 8 == 0
    int wgid = (orig & 7) * 256 + (orig >> 3);  // bijective XCD swizzle
    int rowpair = wgid >> 2, ocg = wgid & 3;    // ocg: 128-oc group == weight chunk
    int n = rowpair >> 6;                       // 64 rowpairs per image
    int h0 = (rowpair & 63) * 2;
    int t = threadIdx.x, wid = t >> 6, lane = t & 63;
    int lp = lane & 15, hi = lane >> 4;
    int rowsel = wid >> 1, whalf = wid & 1;

    i32x4 acc[8][4] = {};

    auto stageX = [&](int cb) {
        // xs: 4 rows x 130 w x 4 q4 = 2080 x 16B, lane-linear LDS dest
#pragma unroll
        for (int i = 0; i < 9; ++i) {
            int idx = t + i * 256;
            if (idx < 2080) {
                int rowk = idx / 520;
                int j = idx - rowk * 520;
                int wr = j >> 2, q4 = j & 3;
                int wg = wr - 1;
                int hh = h0 - 1 + rowk;
                int q4s = q4 ^ ((wr >> 1) & 3);
                const signed char* src = (hh >= 0 && hh < 128 && wg >= 0 && wg < 128)
                    ? qx + (size_t)(n * 128 + hh) * 32768 + wg * 256 + cb * 64 + q4s * 16
                    : zb;
                llds16(src, xs + (size_t)(i * 256 + wid * 64) * 16);
            }
        }
    };
    auto stageW1 = [&](int P, int buf) {    // one (r,s) plane: 512 x 16B, 2 insts/thread
        int cb = P / 9, rs = P % 9;
#pragma unroll
        for (int i = 0; i < 2; ++i) {
            int idx = t + i * 256;          // 0..511
            int oc = idx >> 2, q4 = idx & 3;
            int q4s = q4 ^ ((oc >> 1) & 3);
            const signed char* src = qw
                + (size_t)(rs * 512 + ocg * 128 + oc) * 256 + cb * 64 + q4s * 16;
            llds16(src, &wt[buf][0] + (size_t)idx * 16);
        }
    };

    stageX(0);
    stageW1(0, 0);
    __syncthreads();                        // full drain: xs(0) + plane 0 landed

    for (int cb = 0; cb < 4; ++cb) {
#pragma unroll
        for (int rs = 0; rs < 9; ++rs) {
            int P = cb * 9 + rs;
            if (P < 35) stageW1(P + 1, (P + 1) & 1);   // prefetch next plane
            int r = rs / 3, s = rs - r * 3;
            int rowk = r + rowsel;
            i32x4 a[8], b[4];
#pragma unroll
            for (int mf = 0; mf < 8; ++mf) {
                int ocr = mf * 16 + lp;
                a[mf] = *(const i32x4*)&wt[P & 1][ocr * 64
                                                  + ((hi ^ ((ocr >> 1) & 3)) << 4)];
            }
#pragma unroll
            for (int nf = 0; nf < 4; ++nf) {
                int slot = whalf * 64 + nf * 16 + lp + s;
                b[nf] = *(const i32x4*)&xs[rowk * 8320 + slot * 64
                                           + ((hi ^ ((slot >> 1) & 3)) << 4)];
            }
#pragma unroll
            for (int mf = 0; mf < 8; ++mf)
#pragma unroll
                for (int nf = 0; nf < 4; ++nf)
                    acc[mf][nf] = __builtin_amdgcn_mfma_i32_16x16x64_i8(
                        a[mf], b[nf], acc[mf][nf], 0, 0, 0);
            // ONE barrier: implicit vmcnt(0) drain = next plane landed; and all
            // waves' reads of wt[P&1]/xs are done -> both reusable next phase.
            __syncthreads();
            if (rs == 8 && cb < 3) {
                stageX(cb + 1);             // xs overwrite, now safe
                __syncthreads();            // xs(cb+1) landed
            }
        }
    }

    float sx = fmaxf(__uint_as_float(amaxb[0]), 1e-12f) / 127.0f;
    float sw = fmaxf(__uint_as_float(amaxb[1 + ocg]), 1e-12f) / 127.0f;
    float sc = sx * sw;
    int h = h0 + rowsel;
#pragma unroll
    for (int mf = 0; mf < 8; ++mf)
#pragma unroll
        for (int nf = 0; nf < 4; ++nf)
#pragma unroll
            for (int j = 0; j < 4; ++j) {
                int oc = ocg * 128 + mf * 16 + hi * 4 + j;
                int px = whalf * 64 + nf * 16 + lp;
                out[((size_t)(n * 512 + oc) * 128 + h) * 128 + px] =
                    (float)acc[mf][nf][j] * sc + bias[oc];
            }
}

extern "C" void kernel_launch(void* const* d_in, const int* in_sizes, int n_in,
                              void* d_out, int out_size, void* d_ws, size_t ws_size,
                              hipStream_t stream) {
    const float* x    = (const float*)d_in[0];
    const float* wgt  = (const float*)d_in[1];
    const float* bias = (const float*)d_in[2];
    float* out = (float*)d_out;

    unsigned* amaxb = (unsigned*)d_ws;
    float* part = (float*)((char*)d_ws + 256);
    signed char* qx = (signed char*)d_ws + 16384;
    signed char* qw = (signed char*)d_ws + 16384 + 33554432;
    const signed char* zb = (const signed char*)d_ws + 64;   // 16B zeros for OOB redirect

    hipMemsetAsync(d_ws, 0, 256, stream);   // zb zeros (amax slots overwritten by k_amax2)

    k_amax<<<3200, 256, 0, stream>>>((const float4*)x, (const float4*)wgt, part);
    k_amax2<<<1, 256, 0, stream>>>(part, amaxb);
    k_quant_x<<<1024, 256, 0, stream>>>(x, qx, amaxb);
    k_quant_w<<<512, 256, 0, stream>>>(wgt, qw, amaxb);
    k_conv<<<dim3(2048), 256, 0, stream>>>(qx, qw, zb, amaxb, bias, out);
}

// Round 10
// 229.509 us; speedup vs baseline: 1.8904x; 1.8904x over previous
//
#include <hip/hip_runtime.h>
#include <hip/hip_bf16.h>

// SegmentConv2d: fake-quant-int8 (global for x, per-128-oc-chunk for w) + 3x3 pad1 conv + bias.
// int8 path: quantize to real int8, conv with mfma_i32_16x16x64_i8 (exact int accum),
// scale+bias epilogue.
//
// Shapes: x[8][256][128][128] f32, w[512][256][3][3] f32, bias[512], out[8][512][128][128] f32.
//
// ws layout:
//   [0..63]           : amax[5] (uint bits, written by k_amax2 - no atomics)
//   [64..79]          : 16B zeros (OOB redirect for global_load_lds)
//   [256..13567]      : per-block amax partials float[3328] (x: 0..2047, w: 2048..3199)
//   [16384..)         : qx int8 NHWC  [n][h][w][c]  = 33,554,432 B
//   [16384+32M..)     : qw int8       [r*3+s][oc][c] = 1,179,648 B

typedef int i32x4 __attribute__((ext_vector_type(4)));

__device__ __forceinline__ void llds16(const void* g, void* l) {
    __builtin_amdgcn_global_load_lds(
        (const __attribute__((address_space(1))) void*)g,
        (__attribute__((address_space(3))) void*)l,
        16, 0, 0);
}

__device__ __forceinline__ float f4max(float4 v) {
    return fmaxf(fmaxf(fabsf(v.x), fabsf(v.y)), fmaxf(fabsf(v.z), fabsf(v.w)));
}

__device__ __forceinline__ void barrier_f() {
    asm volatile("" ::: "memory");
    __builtin_amdgcn_s_barrier();
    asm volatile("" ::: "memory");
}

// ---------------- amax stage 1: per-block partial maxima (NO atomics) ----------------
__global__ __launch_bounds__(256) void k_amax(const float4* __restrict__ x,
                                              const float4* __restrict__ w4,
                                              float* __restrict__ part) {
    __shared__ float red[4];
    int t = threadIdx.x;
    float m = 0.f;
    if (blockIdx.x < 2048) {
        int tid = blockIdx.x * 256 + t;
        float4 v[16];
#pragma unroll
        for (int k = 0; k < 16; ++k)
            v[k] = x[(size_t)tid + (size_t)k * 524288];
#pragma unroll
        for (int k = 0; k < 16; ++k) m = fmaxf(m, f4max(v[k]));
    } else {
        int b = blockIdx.x - 2048;          // 0..1151
        int chunk = b / 288;
        int tid = (b - chunk * 288) * 256 + t;
        m = f4max(w4[(size_t)chunk * 73728 + tid]);
    }
    for (int off = 32; off > 0; off >>= 1) m = fmaxf(m, __shfl_xor(m, off, 64));
    if ((t & 63) == 0) red[t >> 6] = m;
    __syncthreads();
    if (t == 0)
        part[blockIdx.x] = fmaxf(fmaxf(red[0], red[1]), fmaxf(red[2], red[3]));
}

// ---------------- amax stage 2: reduce partials -> amaxb[0..4] ----------------
__global__ __launch_bounds__(256) void k_amax2(const float* __restrict__ part,
                                               unsigned* __restrict__ amaxb) {
    __shared__ float red[4];
    int t = threadIdx.x;
    float m = 0.f;
#pragma unroll
    for (int k = 0; k < 8; ++k) m = fmaxf(m, part[t + k * 256]);
    for (int off = 32; off > 0; off >>= 1) m = fmaxf(m, __shfl_xor(m, off, 64));
    if ((t & 63) == 0) red[t >> 6] = m;
    __syncthreads();
    if (t == 0)
        amaxb[0] = __float_as_uint(fmaxf(fmaxf(red[0], red[1]), fmaxf(red[2], red[3])));
    // w: one wave per chunk, 288 partials each
    int c = t >> 6, l = t & 63;
    float wm = 0.f;
#pragma unroll
    for (int k = 0; k < 5; ++k) {
        int i = l + k * 64;
        if (i < 288) wm = fmaxf(wm, part[2048 + c * 288 + i]);
    }
    for (int off = 32; off > 0; off >>= 1) wm = fmaxf(wm, __shfl_xor(wm, off, 64));
    if (l == 0) amaxb[1 + c] = __float_as_uint(wm);
}

// ---------------- quantize x : NCHW f32 -> NHWC int8 ----------------
__global__ __launch_bounds__(256) void k_quant_x(const float* __restrict__ x,
                                                 signed char* __restrict__ qx,
                                                 const unsigned* __restrict__ amaxb) {
    float inv = 127.0f / fmaxf(__uint_as_float(amaxb[0]), 1e-12f);
    int row = blockIdx.x;                 // n*128 + h
    int n = row >> 7, h = row & 127;
    int t = threadIdx.x;
    int w4 = t & 31, cg = t >> 5;         // w4: float4 slot along w; cg in [0,8)
    const float* base = x + (size_t)n * 256 * 16384 + (size_t)h * 128 + w4 * 4;
#pragma unroll
    for (int pp = 0; pp < 2; ++pp) {
        int c0 = pp * 128 + cg * 16;
        float4 v[16];
#pragma unroll
        for (int j = 0; j < 16; ++j)
            v[j] = *(const float4*)(base + (size_t)(c0 + j) * 16384);
#pragma unroll
        for (int i = 0; i < 4; ++i) {
            unsigned wds[4];
#pragma unroll
            for (int jg = 0; jg < 4; ++jg) {
                unsigned u = 0;
#pragma unroll
                for (int jj = 0; jj < 4; ++jj) {
                    float f = (&v[jg * 4 + jj].x)[i];
                    int q = (int)fminf(fmaxf(rintf(f * inv), -128.f), 127.f);
                    u |= ((unsigned)(q & 255)) << (8 * jj);
                }
                wds[jg] = u;
            }
            *(uint4*)&qx[(size_t)row * 32768 + (size_t)(w4 * 4 + i) * 256 + c0] =
                make_uint4(wds[0], wds[1], wds[2], wds[3]);
        }
    }
}

// ---------------- quantize w : OIHW f32 -> [rs][oc][c] int8 ----------------
__global__ void k_quant_w(const float* __restrict__ wsrc, signed char* __restrict__ qw,
                          const unsigned* __restrict__ amaxb) {
    int idx = blockIdx.x * 256 + threadIdx.x;   // 131072 = 512 blocks
    int oc = idx >> 8, c = idx & 255;
    float inv = 127.0f / fmaxf(__uint_as_float(amaxb[1 + (oc >> 7)]), 1e-12f);
    const float* src = wsrc + (size_t)idx * 9;
    float v[9];
#pragma unroll
    for (int rs = 0; rs < 9; ++rs) v[rs] = src[rs];
#pragma unroll
    for (int rs = 0; rs < 9; ++rs) {
        float qf = fminf(fmaxf(rintf(v[rs] * inv), -128.f), 127.f);
        qw[((size_t)(rs * 512 + oc)) * 256 + c] = (signed char)(int)qf;
    }
}

// ---------------- conv : implicit GEMM with mfma_i32_16x16x64_i8 ----------------
// Round-10: round-6 geometry (grid 2048, 4 waves, 128oc x 256px tile, 57.8 KB LDS,
// launch_bounds(256,2) -> 2 blocks/CU, NO spill) + deep counted-vmcnt pipeline:
//  * wt: 3-buffer ring of single 8KB (r,s) planes, staged TWO phases ahead
//    (~2600 cy cover >> L2 latency; r7/r8's 1-subphase cover was the failure).
//  * xs: single buffer [4 rows][130 slots][64c], ROW-rotated: row staged at the
//    phase where it's provably dead (liveness: r=0 reads rows{0,1}, r=1 {1,2},
//    r=2 {2,3}); rows2,3(cb) @ (cb,rs0), row0(cb+1) @ (cb,rs3), row1(cb+1) @ (cb,rs6);
//    every row lands >=3 phases before first read. Halo slots 0/129 zeroed once.
//  * ONE raw s_barrier per phase, preceded by counted s_waitcnt vmcnt(N) from a
//    hand-simulated per-wave FIFO ledger (all stages uniform 2 insts/thread).
//    N never 0 mid-loop. 36 phases x 32 MFMA/wave.
// Round-9's 366us was acc spill (launch_bounds(256,3) caps unified VGPR+AGPR at
// ~170 < needed ~240; WRITE_SIZE tripled). (256,2) is the register-feasible max.
__global__ __launch_bounds__(256, 2) void k_conv(
    const signed char* __restrict__ qx, const signed char* __restrict__ qw,
    const signed char* __restrict__ zb, const unsigned* __restrict__ amaxb,
    const float* __restrict__ bias, float* __restrict__ out) {
    __shared__ __align__(16) signed char xs[4 * 8320];   // 33280 B
    __shared__ __align__(16) signed char wt[3 * 8192];   // 24576 B  (57856 total)
    int orig = blockIdx.x;                      // 0..2047, nwg % 8 == 0
    int wgid = (orig & 7) * 256 + (orig >> 3);  // bijective XCD swizzle
    int rowpair = wgid >> 2, ocg = wgid & 3;    // ocg: 128-oc group == weight chunk
    int n = rowpair >> 6;                       // 64 rowpairs per image
    int h0 = (rowpair & 63) * 2;
    int t = threadIdx.x, wid = t >> 6, lane = t & 63;
    int lp = lane & 15, hi = lane >> 4;
    int rowsel = wid >> 1, whalf = wid & 1;

    i32x4 acc[8][4] = {};

    auto stW = [&](int P) {                     // one (r,s) plane: 2 insts/thread
        int cb = P / 9, rs = P % 9;
#pragma unroll
        for (int i = 0; i < 2; ++i) {
            int idx = t + i * 256;              // 0..511
            int oc = idx >> 2, q4 = idx & 3;
            int q4s = q4 ^ ((oc >> 1) & 3);
            const signed char* src = qw
                + (size_t)(rs * 512 + ocg * 128 + oc) * 256 + cb * 64 + q4s * 16;
            llds16(src, wt + (P % 3) * 8192 + idx * 16);
        }
    };
    auto stXrow = [&](int cb, int rowk) {       // one input row: 2 insts/thread
        int hh = h0 - 1 + rowk;
#pragma unroll
        for (int i = 0; i < 2; ++i) {
            int idx = t + i * 256;              // 0..511 -> w=idx>>2, q4=idx&3
            int w = idx >> 2, q4 = idx & 3;
            int q4s = q4 ^ (((w + 1) >> 1) & 3);   // slot = w+1 read-swizzle inverse
            const signed char* src = (hh >= 0 && hh < 128)
                ? qx + (size_t)(n * 128 + hh) * 32768 + w * 256 + cb * 64 + q4s * 16
                : zb;
            llds16(src, xs + rowk * 8320 + 64 + idx * 16);
        }
    };

    // prologue: zero w-halo slots (0,129 of each row; never re-staged), stage
    // all of xs(cb0) + planes 0,1. Wait X+plane0 (allow plane1 in flight).
    if (t < 32) {
        int unit = t >> 2, q = t & 3;
        int rowk = unit >> 1, side = unit & 1;
        *(i32x4*)&xs[rowk * 8320 + (side ? 129 : 0) * 64 + q * 16] = i32x4{0, 0, 0, 0};
    }
    stXrow(0, 0); stXrow(0, 1); stXrow(0, 2); stXrow(0, 3);
    stW(0); stW(1);
    asm volatile("s_waitcnt vmcnt(2)" ::: "memory");
    asm volatile("s_waitcnt lgkmcnt(0)" ::: "memory");
    barrier_f();

#define PHASE(P, NWAIT)                                                       \
    {                                                                         \
        constexpr int cb_ = (P) / 9, rs_ = (P) % 9, r_ = rs_ / 3,             \
                      s_ = rs_ % 3;                                           \
        if ((P) + 2 <= 35) stW((P) + 2);                                      \
        if (rs_ == 0 && cb_ >= 1) { stXrow(cb_, 2); stXrow(cb_, 3); }         \
        if (rs_ == 3 && cb_ <= 2) stXrow(cb_ + 1, 0);                         \
        if (rs_ == 6 && cb_ <= 2) stXrow(cb_ + 1, 1);                         \
        i32x4 a[8], b[4];                                                     \
        _Pragma("unroll")                                                     \
        for (int mf = 0; mf < 8; ++mf) {                                      \
            int ocr = mf * 16 + lp;                                           \
            a[mf] = *(const i32x4*)&wt[((P) % 3) * 8192 + ocr * 64            \
                                       + ((hi ^ ((ocr >> 1) & 3)) << 4)];     \
        }                                                                     \
        _Pragma("unroll")                                                     \
        for (int nf = 0; nf < 4; ++nf) {                                      \
            int slot = whalf * 64 + nf * 16 + lp + s_;                        \
            b[nf] = *(const i32x4*)&xs[(r_ + rowsel) * 8320 + slot * 64       \
                                       + ((hi ^ ((slot >> 1) & 3)) << 4)];    \
        }                                                                     \
        __builtin_amdgcn_s_setprio(1);                                        \
        _Pragma("unroll")                                                     \
        for (int mf = 0; mf < 8; ++mf)                                        \
            _Pragma("unroll")                                                 \
            for (int nf = 0; nf < 4; ++nf)                                    \
                acc[mf][nf] = __builtin_amdgcn_mfma_i32_16x16x64_i8(          \
                    a[mf], b[nf], acc[mf][nf], 0, 0, 0);                      \
        __builtin_amdgcn_s_setprio(0);                                        \
        if ((P) < 35) {                                                       \
            asm volatile("s_waitcnt vmcnt(" #NWAIT ")" ::: "memory");         \
            barrier_f();                                                      \
        }                                                                     \
    }

    // FIFO-simulated vmcnt constants (see header comment)
    PHASE(0, 2)  PHASE(1, 2)  PHASE(2, 2)  PHASE(3, 4)  PHASE(4, 4)  PHASE(5, 2)
    PHASE(6, 4)  PHASE(7, 4)  PHASE(8, 2)  PHASE(9, 6)  PHASE(10, 6) PHASE(11, 2)
    PHASE(12, 4) PHASE(13, 4) PHASE(14, 2) PHASE(15, 4) PHASE(16, 4) PHASE(17, 2)
    PHASE(18, 6) PHASE(19, 6) PHASE(20, 2) PHASE(21, 4) PHASE(22, 4) PHASE(23, 2)
    PHASE(24, 4) PHASE(25, 4) PHASE(26, 2) PHASE(27, 6) PHASE(28, 6) PHASE(29, 2)
    PHASE(30, 2) PHASE(31, 2) PHASE(32, 2) PHASE(33, 2) PHASE(34, 0) PHASE(35, 0)
#undef PHASE

    float sx = fmaxf(__uint_as_float(amaxb[0]), 1e-12f) / 127.0f;
    float sw = fmaxf(__uint_as_float(amaxb[1 + ocg]), 1e-12f) / 127.0f;
    float sc = sx * sw;
    int h = h0 + rowsel;
#pragma unroll
    for (int mf = 0; mf < 8; ++mf)
#pragma unroll
        for (int nf = 0; nf < 4; ++nf)
#pragma unroll
            for (int j = 0; j < 4; ++j) {
                int oc = ocg * 128 + mf * 16 + hi * 4 + j;
                int px = whalf * 64 + nf * 16 + lp;
                out[((size_t)(n * 512 + oc) * 128 + h) * 128 + px] =
                    (float)acc[mf][nf][j] * sc + bias[oc];
            }
}

extern "C" void kernel_launch(void* const* d_in, const int* in_sizes, int n_in,
                              void* d_out, int out_size, void* d_ws, size_t ws_size,
                              hipStream_t stream) {
    const float* x    = (const float*)d_in[0];
    const float* wgt  = (const float*)d_in[1];
    const float* bias = (const float*)d_in[2];
    float* out = (float*)d_out;

    unsigned* amaxb = (unsigned*)d_ws;
    float* part = (float*)((char*)d_ws + 256);
    signed char* qx = (signed char*)d_ws + 16384;
    signed char* qw = (signed char*)d_ws + 16384 + 33554432;
    const signed char* zb = (const signed char*)d_ws + 64;   // 16B zeros for OOB redirect

    hipMemsetAsync(d_ws, 0, 256, stream);   // zb zeros (amax slots overwritten by k_amax2)

    k_amax<<<3200, 256, 0, stream>>>((const float4*)x, (const float4*)wgt, part);
    k_amax2<<<1, 256, 0, stream>>>(part, amaxb);
    k_quant_x<<<1024, 256, 0, stream>>>(x, qx, amaxb);
    k_quant_w<<<512, 256, 0, stream>>>(wgt, qw, amaxb);
    k_conv<<<dim3(2048), 256, 0, stream>>>(qx, qw, zb, amaxb, bias, out);
}